// Round 5
// baseline (533.450 us; speedup 1.0000x reference)
//
#include <hip/hip_runtime.h>
#include <hip/hip_bf16.h>

#define AS1 __attribute__((address_space(1)))
#define AS3 __attribute__((address_space(3)))

typedef __attribute__((ext_vector_type(8))) short short8;
typedef __attribute__((ext_vector_type(4))) short short4v;
typedef __attribute__((ext_vector_type(4))) float f32x4;

constexpr int S_ = 2048;
constexpr int HID_ = 4096;
constexpr int NH = 32;       // q heads
constexpr int NKH = 8;       // kv heads
constexpr float EPS_ = 1e-5f;
constexpr float SCALE_ = 0.08838834764831845f;   // 128^-0.5
constexpr float SCL2E_ = 0.12751879524622712f;   // SCALE * log2(e)

__device__ __forceinline__ short f2bf(float f) {
  __hip_bfloat16 h = __float2bfloat16(f);
  return *reinterpret_cast<short*>(&h);
}

// ---------------- fused fp32 -> bf16 cast (all 5 inputs, 1 launch) ------
// float4-unit segment bounds: hidden 2M | Wq 4M | Wk 1M | Wv 1M | Wo 4M
__global__ __launch_bounds__(256) void cast_all_kernel(
    const float4* __restrict__ h, const float4* __restrict__ wq,
    const float4* __restrict__ wk, const float4* __restrict__ wv,
    const float4* __restrict__ wo,
    short4v* __restrict__ hd, short4v* __restrict__ wqkvd,
    short4v* __restrict__ wod) {
  long i = (long)blockIdx.x * 256 + threadIdx.x;
  const float4* s;
  short4v* d;
  long o;
  if (i < 2097152L)        { s = h;  d = hd;              o = i; }
  else if (i < 6291456L)   { s = wq; d = wqkvd;           o = i - 2097152L; }
  else if (i < 7340032L)   { s = wk; d = wqkvd + 4194304L; o = i - 6291456L; }
  else if (i < 8388608L)   { s = wv; d = wqkvd + 5242880L; o = i - 7340032L; }
  else                     { s = wo; d = wod;             o = i - 8388608L; }
  float4 v = s[o];
  short4v r;
  r[0] = f2bf(v.x); r[1] = f2bf(v.y); r[2] = f2bf(v.z); r[3] = f2bf(v.w);
  d[o] = r;
}

// ================= 256 x (G*64) 8-phase bf16 GEMM (C = A * B^T) =========
// M == 2048 in all uses (8 row-tiles). wg -> (bx = wg/8, by = wg%8) so the
// 32 consecutive wg per XCD chunk share B column-panels in that XCD's L2.
template <int G>
__global__ __launch_bounds__(512, 2) void gemm8_bt(const short* __restrict__ A,
                                                   const short* __restrict__ B,
                                                   float* __restrict__ C,
                                                   int M, int N, int K) {
  constexpr int BN = G * 64;
  constexpr int BUFSZ = 32768 + G * 8192;
  constexpr int GH = (G + 1) / 2;
  extern __shared__ __align__(16) char smem[];
  const int t = threadIdx.x, w = t >> 6, lane = t & 63;
  int wg = blockIdx.x;
  const int cpx = gridDim.x >> 3;               // grid % 8 == 0
  wg = (wg & 7) * cpx + (wg >> 3);              // XCD-chunked swizzle
  const int by = wg & 7, bx = wg >> 3;          // by fast: B-panel reuse in L2
  const long m0 = (long)by * 256, n0 = (long)bx * BN;
  const int wr = w >> 2, wc = w & 3;
  const int l15 = lane & 15, l4 = lane >> 4;
  const int NT = K >> 6;

  f32x4 acc[8][G];
#pragma unroll
  for (int f = 0; f < 8; ++f)
#pragma unroll
    for (int g = 0; g < G; ++g) acc[f][g] = (f32x4){0.f, 0.f, 0.f, 0.f};

  const int srow = w * 8 + (lane >> 3);
  const int schunk = lane & 7;

  auto STAGE = [&](int tile, int unit) {
    int tb = tile & (NT - 1);
    long k0 = (long)tb << 6;
    char* base = smem + (tb & 1) * BUFSZ;
    if (unit < 2) {
#pragma unroll
      for (int j = 0; j < 2; ++j) {
        int row = unit * 128 + j * 64 + srow;
        int ch = schunk ^ (row & 7);
        __builtin_amdgcn_global_load_lds(
            (const AS1 void*)(A + (m0 + row) * K + k0 + ch * 8),
            (AS3 void*)(base + unit * 16384 + j * 8192 + w * 1024 + lane * 16), 16, 0, 0);
      }
    } else {
      int bj = unit - 2;
      int row = bj * 64 + srow;
      int ch = schunk ^ (row & 7);
      __builtin_amdgcn_global_load_lds(
          (const AS1 void*)(B + (n0 + row) * K + k0 + ch * 8),
          (AS3 void*)(base + 32768 + bj * 8192 + w * 1024 + lane * 16), 16, 0, 0);
    }
  };
  auto LDA = [&](int buf, int f, int s) -> short8 {
    int ra = wr * 128 + f * 16 + l15;
    int byte = ra * 128 + (((s << 2) + l4) ^ (ra & 7)) * 16;
    return *(const short8*)(smem + buf * BUFSZ + byte);
  };
  auto LDB = [&](int buf, int g, int s) -> short8 {
    int rb = wc * (G * 16) + g * 16 + l15;
    int byte = 32768 + rb * 128 + (((s << 2) + l4) ^ (rb & 7)) * 16;
    return *(const short8*)(smem + buf * BUFSZ + byte);
  };

#pragma unroll
  for (int u = 0; u < 2 + G; ++u) STAGE(0, u);
  STAGE(1, 0);
  asm volatile("s_waitcnt vmcnt(2)" ::: "memory");
  asm volatile("s_barrier" ::: "memory");

  short8 af[4][2], bf2[G][2];
  for (int tt = 0; tt < NT; ++tt) {
    const int buf = tt & 1;
    // q0
#pragma unroll
    for (int f = 0; f < 4; ++f) { af[f][0] = LDA(buf, f, 0); af[f][1] = LDA(buf, f, 1); }
#pragma unroll
    for (int g = 0; g < GH; ++g) { bf2[g][0] = LDB(buf, g, 0); bf2[g][1] = LDB(buf, g, 1); }
    STAGE(tt + 1, 1);
    asm volatile("s_barrier" ::: "memory");
    __builtin_amdgcn_s_setprio(1);
#pragma unroll
    for (int f = 0; f < 4; ++f)
#pragma unroll
      for (int g = 0; g < GH; ++g) {
        acc[f][g] = __builtin_amdgcn_mfma_f32_16x16x32_bf16(af[f][0], bf2[g][0], acc[f][g], 0, 0, 0);
        acc[f][g] = __builtin_amdgcn_mfma_f32_16x16x32_bf16(af[f][1], bf2[g][1], acc[f][g], 0, 0, 0);
      }
    __builtin_amdgcn_s_setprio(0);
    asm volatile("s_barrier" ::: "memory");
    // q1
#pragma unroll
    for (int g = GH; g < G; ++g) { bf2[g][0] = LDB(buf, g, 0); bf2[g][1] = LDB(buf, g, 1); }
#pragma unroll
    for (int u = 2; u < G + 1; ++u) STAGE(tt + 1, u);
    asm volatile("s_barrier" ::: "memory");
    __builtin_amdgcn_s_setprio(1);
#pragma unroll
    for (int f = 0; f < 4; ++f)
#pragma unroll
      for (int g = GH; g < G; ++g) {
        acc[f][g] = __builtin_amdgcn_mfma_f32_16x16x32_bf16(af[f][0], bf2[g][0], acc[f][g], 0, 0, 0);
        acc[f][g] = __builtin_amdgcn_mfma_f32_16x16x32_bf16(af[f][1], bf2[g][1], acc[f][g], 0, 0, 0);
      }
    __builtin_amdgcn_s_setprio(0);
    asm volatile("s_barrier" ::: "memory");
    // q2
#pragma unroll
    for (int f = 0; f < 4; ++f) { af[f][0] = LDA(buf, 4 + f, 0); af[f][1] = LDA(buf, 4 + f, 1); }
    STAGE(tt + 1, G + 1);
    asm volatile("s_barrier" ::: "memory");
    __builtin_amdgcn_s_setprio(1);
#pragma unroll
    for (int f = 0; f < 4; ++f)
#pragma unroll
      for (int g = 0; g < GH; ++g) {
        acc[4 + f][g] = __builtin_amdgcn_mfma_f32_16x16x32_bf16(af[f][0], bf2[g][0], acc[4 + f][g], 0, 0, 0);
        acc[4 + f][g] = __builtin_amdgcn_mfma_f32_16x16x32_bf16(af[f][1], bf2[g][1], acc[4 + f][g], 0, 0, 0);
      }
    __builtin_amdgcn_s_setprio(0);
    asm volatile("s_barrier" ::: "memory");
    // q3
    STAGE(tt + 2, 0);
    asm volatile("s_barrier" ::: "memory");
    __builtin_amdgcn_s_setprio(1);
#pragma unroll
    for (int f = 0; f < 4; ++f)
#pragma unroll
      for (int g = GH; g < G; ++g) {
        acc[4 + f][g] = __builtin_amdgcn_mfma_f32_16x16x32_bf16(af[f][0], bf2[g][0], acc[4 + f][g], 0, 0, 0);
        acc[4 + f][g] = __builtin_amdgcn_mfma_f32_16x16x32_bf16(af[f][1], bf2[g][1], acc[4 + f][g], 0, 0, 0);
      }
    __builtin_amdgcn_s_setprio(0);
    asm volatile("s_waitcnt vmcnt(2)" ::: "memory");
    asm volatile("s_barrier" ::: "memory");
  }
#pragma unroll
  for (int f = 0; f < 8; ++f)
#pragma unroll
    for (int g = 0; g < G; ++g)
#pragma unroll
      for (int r = 0; r < 4; ++r) {
        long m = m0 + wr * 128 + f * 16 + l4 * 4 + r;
        long n = n0 + wc * (G * 16) + g * 16 + l15;
        C[m * N + n] = acc[f][g][r];
      }
}

// ---------------- RMS norm + partial RoPE (Q and K only) --------------
// Q gets SCALE*log2(e) folded in (scores computed in log2 domain).
__global__ __launch_bounds__(256) void normrope_kernel(const float* __restrict__ QKV,
    const int* __restrict__ pos_ids, const float* __restrict__ qw,
    const float* __restrict__ kw,
    short* __restrict__ Qn, short* __restrict__ Kn) {
  const int lane = threadIdx.x & 63;
  const long row = (long)blockIdx.x * 4 + (threadIdx.x >> 6);
  const long NQ = (long)S_ * NH;
  const float* src;
  short* dst;
  const float* wv;
  int s;
  float scl = 1.f;
  if (row < NQ) {
    s = (int)(row >> 5); int h = (int)(row & 31);
    src = QKV + (long)s * 6144 + h * 128;
    dst = Qn + ((long)h * S_ + s) * 128;
    wv = qw; scl = SCL2E_;
  } else {
    long r2 = row - NQ; s = (int)(r2 >> 3); int kh = (int)(r2 & 7);
    src = QKV + (long)s * 6144 + 4096 + kh * 128;
    dst = Kn + ((long)kh * S_ + s) * 128;
    wv = kw;
  }
  float x0 = src[lane], x1 = src[lane + 64];
  float ss = x0 * x0 + x1 * x1;
#pragma unroll
  for (int m = 1; m < 64; m <<= 1) ss += __shfl_xor(ss, m);
  float inv = rsqrtf(ss * (1.f / 128.f) + EPS_);
  x0 = x0 * inv * (wv[lane] + 1.f);
  x1 = x1 * inv * (wv[lane + 64] + 1.f);
  int pos = pos_ids[s];
  int i = lane & 31;
  float invf = expf(-logf(10000.f) * ((float)(2 * i) / 64.f));
  float f = (float)pos * invf;
  float c = cosf(f), sn = sinf(f);
  float p = __shfl_xor(x0, 32);
  x0 = (lane < 32) ? (x0 * c - p * sn) : (x0 * c + p * sn);
  dst[lane] = f2bf(x0 * scl);
  dst[lane + 64] = f2bf(x1 * scl);
}

// ---------------- V transpose: QKVf V-cols -> Vt[kh][128][S] bf16 ------
__global__ __launch_bounds__(256) void vtrans_kernel(const float* __restrict__ QKV,
                                                     short* __restrict__ Vt) {
  __shared__ __align__(16) float lt[64][68];
  const int t = threadIdx.x;
  const int s0 = blockIdx.x * 64, d0 = blockIdx.y * 64, kh = blockIdx.z;
  const float* src = QKV + (long)s0 * 6144 + 5120 + kh * 128 + d0;
#pragma unroll
  for (int i = 0; i < 4; ++i) {
    int idx = t + i * 256;
    int r = idx >> 4, c4 = (idx & 15) * 4;
    float4 v = *(const float4*)(src + (long)r * 6144 + c4);
    *(float4*)&lt[r][c4] = v;
  }
  __syncthreads();
  int d = t >> 2, seg = (t & 3) * 16;
  short* dst = Vt + ((long)kh * 128 + d0 + d) * S_ + s0 + seg;
  short8 a, b2;
#pragma unroll
  for (int j = 0; j < 8; ++j) a[j] = f2bf(lt[seg + j][d]);
#pragma unroll
  for (int j = 0; j < 8; ++j) b2[j] = f2bf(lt[seg + 8 + j][d]);
  *(short8*)dst = a;
  *(short8*)(dst + 8) = b2;
}

// ---------------- causal flash attention, GQA 4:1 ----------------------
// 512 blocks (h, qt desc), 4 waves x 32 q-rows (QBLK=128), KVBLK=64.
// K/V double-buffered in LDS (stage t+1 issued before compute of t).
// LDS: K[2][16K] V[2][16K] P[4][4K] = 80 KB -> 2 blocks/CU.
__global__ __launch_bounds__(256, 2) void attn_kernel(const short* __restrict__ Qn,
    const short* __restrict__ Kn, const short* __restrict__ Vt,
    short* __restrict__ O) {
  extern __shared__ __align__(16) char smem[];
  const int t = threadIdx.x, w = t >> 6, lane = t & 63;
  const int b = blockIdx.x;
  const int h = b & 31, qt = 15 - (b >> 5);
  const int kh = h >> 2;
  const int q0 = qt * 128;
  const int l15 = lane & 15, l4 = lane >> 4, lk = l4 * 8;
  const int mrow = l4 * 4;
  char* pw = smem + 65536 + w * 4096;

  // Q fragments: 2 m-frags x 4 k-frags (rows q0 + w*32 + mf*16 + l15)
  short8 qf[2][4];
  {
    const short* Qh = Qn + ((long)h * S_ + q0 + w * 32) * 128;
#pragma unroll
    for (int mf = 0; mf < 2; ++mf)
#pragma unroll
      for (int ks = 0; ks < 4; ++ks)
        qf[mf][ks] = *(const short8*)(Qh + (mf * 16 + l15) * 128 + ks * 32 + lk);
  }
  f32x4 o[2][8];
#pragma unroll
  for (int mf = 0; mf < 2; ++mf)
#pragma unroll
    for (int nf = 0; nf < 8; ++nf) o[mf][nf] = (f32x4){0.f, 0.f, 0.f, 0.f};
  float mrun[2][4], lrun[2][4];
#pragma unroll
  for (int mf = 0; mf < 2; ++mf)
#pragma unroll
    for (int r = 0; r < 4; ++r) { mrun[mf][r] = -1e30f; lrun[mf][r] = 0.f; }

  const short* Khp = Kn + (long)kh * S_ * 128;
  const short* Vtp = Vt + (long)kh * 128 * S_;
  const int NTIL = 2 * qt + 2;

  // staging: per tile 8 glds/thread (4 K + 4 V), linear LDS dest,
  // pre-swizzled global source (chunk ^= row&7).
  auto STAGE = [&](int it) {
    const int kv0 = it * 64;
    char* kd = smem + (it & 1) * 16384;
    char* vd = smem + 32768 + (it & 1) * 16384;
#pragma unroll
    for (int j = 0; j < 4; ++j) {
      int row = (w * 4 + j) * 4 + l4;              // K row 0..63
      int ch = l15 ^ (row & 7);                    // 16 chunks, xor low3
      __builtin_amdgcn_global_load_lds(
          (const AS1 void*)(Khp + (long)(kv0 + row) * 128 + ch * 8),
          (AS3 void*)(kd + (w * 4 + j) * 1024 + lane * 16), 16, 0, 0);
    }
#pragma unroll
    for (int j = 0; j < 4; ++j) {
      int d = (w * 4 + j) * 8 + (lane >> 3);       // V^T d-row 0..127
      int ch = (lane & 7) ^ (d & 7);               // 8 chunks
      __builtin_amdgcn_global_load_lds(
          (const AS1 void*)(Vtp + (long)d * S_ + kv0 + ch * 8),
          (AS3 void*)(vd + (w * 4 + j) * 1024 + lane * 16), 16, 0, 0);
    }
  };

  STAGE(0);
  asm volatile("s_waitcnt vmcnt(0)" ::: "memory");
  asm volatile("s_barrier" ::: "memory");

  for (int it = 0; it < NTIL; ++it) {
    const int kv0 = it * 64;
    const char* kd = smem + (it & 1) * 16384;
    const char* vd = smem + 32768 + (it & 1) * 16384;
    if (it + 1 < NTIL) STAGE(it + 1);

    if (kv0 < q0 + w * 32 + 32) {                  // wave active
      // ---- QK^T: 32x64 scores (2 m-frags) ----
      f32x4 sc[2][4];
#pragma unroll
      for (int mf = 0; mf < 2; ++mf)
#pragma unroll
        for (int ni = 0; ni < 4; ++ni) sc[mf][ni] = (f32x4){0.f, 0.f, 0.f, 0.f};
#pragma unroll
      for (int ks = 0; ks < 4; ++ks)
#pragma unroll
        for (int ni = 0; ni < 4; ++ni) {
          int row = ni * 16 + l15;
          int bb = row * 256 + ((((ks << 2) + l4) ^ (row & 7)) << 4);
          short8 kf = *(const short8*)(kd + bb);
          sc[0][ni] = __builtin_amdgcn_mfma_f32_16x16x32_bf16(qf[0][ks], kf, sc[0][ni], 0, 0, 0);
          sc[1][ni] = __builtin_amdgcn_mfma_f32_16x16x32_bf16(qf[1][ks], kf, sc[1][ni], 0, 0, 0);
        }
      // ---- causal mask ----
#pragma unroll
      for (int mf = 0; mf < 2; ++mf)
        if (kv0 + 64 > q0 + w * 32 + mf * 16) {
#pragma unroll
          for (int ni = 0; ni < 4; ++ni)
#pragma unroll
            for (int r = 0; r < 4; ++r) {
              int qm = q0 + w * 32 + mf * 16 + mrow + r;
              int kcol = kv0 + ni * 16 + l15;
              if (kcol > qm) sc[mf][ni][r] = -1e30f;
            }
        }
      // ---- online softmax (log2 domain, exp2) + P write ----
#pragma unroll
      for (int mf = 0; mf < 2; ++mf)
#pragma unroll
        for (int r = 0; r < 4; ++r) {
          float mx = fmaxf(fmaxf(sc[mf][0][r], sc[mf][1][r]), fmaxf(sc[mf][2][r], sc[mf][3][r]));
          mx = fmaxf(mx, __shfl_xor(mx, 1));
          mx = fmaxf(mx, __shfl_xor(mx, 2));
          mx = fmaxf(mx, __shfl_xor(mx, 4));
          mx = fmaxf(mx, __shfl_xor(mx, 8));
          float mnew = fmaxf(mrun[mf][r], mx);
          float scale = exp2f(mrun[mf][r] - mnew);
          mrun[mf][r] = mnew;
          float ssum = 0.f;
          short pbv[4];
#pragma unroll
          for (int ni = 0; ni < 4; ++ni) {
            float p = exp2f(sc[mf][ni][r] - mnew);
            ssum += p;
            pbv[ni] = f2bf(p);
          }
          ssum += __shfl_xor(ssum, 1);
          ssum += __shfl_xor(ssum, 2);
          ssum += __shfl_xor(ssum, 4);
          ssum += __shfl_xor(ssum, 8);
          lrun[mf][r] = lrun[mf][r] * scale + ssum;
#pragma unroll
          for (int nf = 0; nf < 8; ++nf) o[mf][nf][r] *= scale;
          int m = mf * 16 + mrow + r;
#pragma unroll
          for (int ni = 0; ni < 4; ++ni) {
            int bb = (m * 128 + (ni * 16 + l15) * 2) ^ ((m & 7) << 4);
            *(short*)(pw + bb) = pbv[ni];
          }
        }
      // ---- PV: O(32x128) += P(32x64) * V^T ----
#pragma unroll
      for (int ks2 = 0; ks2 < 2; ++ks2) {
        int rq0 = l15, rq1 = 16 + l15;
        short8 pf0 = *(const short8*)(pw + ((rq0 * 128 + (ks2 * 32 + lk) * 2) ^ ((rq0 & 7) << 4)));
        short8 pf1 = *(const short8*)(pw + ((rq1 * 128 + (ks2 * 32 + lk) * 2) ^ ((rq1 & 7) << 4)));
#pragma unroll
        for (int nf = 0; nf < 8; ++nf) {
          int d = nf * 16 + l15;
          int bv = d * 128 + ((((ks2 << 2) + l4) ^ (d & 7)) << 4);
          short8 vf = *(const short8*)(vd + bv);
          o[0][nf] = __builtin_amdgcn_mfma_f32_16x16x32_bf16(pf0, vf, o[0][nf], 0, 0, 0);
          o[1][nf] = __builtin_amdgcn_mfma_f32_16x16x32_bf16(pf1, vf, o[1][nf], 0, 0, 0);
        }
      }
    }
    asm volatile("s_waitcnt vmcnt(0)" ::: "memory");   // tile t+1 landed (issued ~600cy ago)
    asm volatile("s_barrier" ::: "memory");
  }
  // ---- epilogue ----
#pragma unroll
  for (int mf = 0; mf < 2; ++mf)
#pragma unroll
    for (int r = 0; r < 4; ++r) {
      float invl = 1.f / lrun[mf][r];
      int m = q0 + w * 32 + mf * 16 + mrow + r;
#pragma unroll
      for (int nf = 0; nf < 8; ++nf)
        O[(long)m * 4096 + h * 128 + nf * 16 + l15] = f2bf(o[mf][nf][r] * invl);
    }
}

// ---------------- launch -----------------------------------------------
extern "C" void kernel_launch(void* const* d_in, const int* in_sizes, int n_in,
                              void* d_out, int out_size, void* d_ws, size_t ws_size,
                              hipStream_t stream) {
  const float* hidden = (const float*)d_in[0];
  const float* Wq = (const float*)d_in[1];
  const float* Wk = (const float*)d_in[2];
  const float* Wv = (const float*)d_in[3];
  const float* Wo = (const float*)d_in[4];
  const float* qw = (const float*)d_in[5];
  const float* kw = (const float*)d_in[6];
  const int* pos = (const int*)d_in[7];
  float* out = (float*)d_out;

  char* ws = (char*)d_ws;
  short* hid_bf  = (short*)(ws + 0);              // 16 MB (dead after GEMM1)
  short* Wqkv_bf = (short*)(ws + 16777216L);      // 48 MB
  short* Wo_bf   = (short*)(ws + 67108864L);      // 32 MB
  float* QKVf    = (float*)(ws + 100663296L);     // 48 MB
  short* Qn      = (short*)(ws + 150994944L);     // 16 MB
  short* Kn      = (short*)(ws + 167772160L);     // 4 MB
  short* Vt      = (short*)(ws + 171966464L);     // 4 MB
  short* AO      = hid_bf;                        // alias

  (void)hipFuncSetAttribute((const void*)gemm8_bt<3>,
                            hipFuncAttributeMaxDynamicSharedMemorySize, 114688);
  (void)hipFuncSetAttribute((const void*)gemm8_bt<2>,
                            hipFuncAttributeMaxDynamicSharedMemorySize, 98304);
  (void)hipFuncSetAttribute((const void*)attn_kernel,
                            hipFuncAttributeMaxDynamicSharedMemorySize, 81920);

  // all fp32->bf16 casts in one launch (12M float4)
  cast_all_kernel<<<49152, 256, 0, stream>>>(
      (const float4*)hidden, (const float4*)Wq, (const float4*)Wk,
      (const float4*)Wv, (const float4*)Wo,
      (short4v*)hid_bf, (short4v*)Wqkv_bf, (short4v*)Wo_bf);

  // QKV = hidden @ [Wq;Wk;Wv]^T : M=2048, N=6144, K=4096 -> 256 blocks
  gemm8_bt<3><<<dim3(256), 512, 114688, stream>>>(hid_bf, Wqkv_bf, QKVf, S_, 6144, HID_);

  normrope_kernel<<<(S_ * (NH + NKH)) / 4, 256, 0, stream>>>(QKVf, pos, qw, kw, Qn, Kn);
  vtrans_kernel<<<dim3(S_ / 64, 2, NKH), 256, 0, stream>>>(QKVf, Vt);

  // attention: 512 blocks (h, qt desc), 256 thr, 80 KB LDS
  attn_kernel<<<dim3(512), 256, 81920, stream>>>(Qn, Kn, Vt, AO);

  // out = AO @ Wo^T : M=2048, N=4096, K=4096 -> 256 blocks
  gemm8_bt<2><<<dim3(256), 512, 98304, stream>>>(AO, Wo_bf, out, S_, HID_, HID_);
}

// Round 6
// 515.487 us; speedup vs baseline: 1.0348x; 1.0348x over previous
//
#include <hip/hip_runtime.h>
#include <hip/hip_bf16.h>

#define AS1 __attribute__((address_space(1)))
#define AS3 __attribute__((address_space(3)))

typedef __attribute__((ext_vector_type(8))) short short8;
typedef __attribute__((ext_vector_type(4))) short short4v;
typedef __attribute__((ext_vector_type(4))) float f32x4;

constexpr int S_ = 2048;
constexpr int HID_ = 4096;
constexpr int NH = 32;       // q heads
constexpr int NKH = 8;       // kv heads
constexpr float EPS_ = 1e-5f;
constexpr float SCALE_ = 0.08838834764831845f;   // 128^-0.5
constexpr float SCL2E_ = 0.12751879524622712f;   // SCALE * log2(e)

__device__ __forceinline__ short f2bf(float f) {
  __hip_bfloat16 h = __float2bfloat16(f);
  return *reinterpret_cast<short*>(&h);
}

// ---------------- fused fp32 -> bf16 cast (all 5 inputs, 1 launch) ------
__global__ __launch_bounds__(256) void cast_all_kernel(
    const float4* __restrict__ h, const float4* __restrict__ wq,
    const float4* __restrict__ wk, const float4* __restrict__ wv,
    const float4* __restrict__ wo,
    short4v* __restrict__ hd, short4v* __restrict__ wqkvd,
    short4v* __restrict__ wod) {
  long i = (long)blockIdx.x * 256 + threadIdx.x;
  const float4* s;
  short4v* d;
  long o;
  if (i < 2097152L)        { s = h;  d = hd;              o = i; }
  else if (i < 6291456L)   { s = wq; d = wqkvd;           o = i - 2097152L; }
  else if (i < 7340032L)   { s = wk; d = wqkvd + 4194304L; o = i - 6291456L; }
  else if (i < 8388608L)   { s = wv; d = wqkvd + 5242880L; o = i - 7340032L; }
  else                     { s = wo; d = wod;             o = i - 8388608L; }
  float4 v = s[o];
  short4v r;
  r[0] = f2bf(v.x); r[1] = f2bf(v.y); r[2] = f2bf(v.z); r[3] = f2bf(v.w);
  d[o] = r;
}

// ================= 256 x (G*64) 8-phase bf16 GEMM (C = A * B^T) =========
template <int G>
__global__ __launch_bounds__(512, 2) void gemm8_bt(const short* __restrict__ A,
                                                   const short* __restrict__ B,
                                                   float* __restrict__ C,
                                                   int M, int N, int K) {
  constexpr int BN = G * 64;
  constexpr int BUFSZ = 32768 + G * 8192;
  constexpr int GH = (G + 1) / 2;
  extern __shared__ __align__(16) char smem[];
  const int t = threadIdx.x, w = t >> 6, lane = t & 63;
  int wg = blockIdx.x;
  const int cpx = gridDim.x >> 3;               // grid % 8 == 0
  wg = (wg & 7) * cpx + (wg >> 3);              // XCD-chunked swizzle
  const int by = wg & 7, bx = wg >> 3;          // by fast: B-panel reuse in L2
  const long m0 = (long)by * 256, n0 = (long)bx * BN;
  const int wr = w >> 2, wc = w & 3;
  const int l15 = lane & 15, l4 = lane >> 4;
  const int NT = K >> 6;

  f32x4 acc[8][G];
#pragma unroll
  for (int f = 0; f < 8; ++f)
#pragma unroll
    for (int g = 0; g < G; ++g) acc[f][g] = (f32x4){0.f, 0.f, 0.f, 0.f};

  const int srow = w * 8 + (lane >> 3);
  const int schunk = lane & 7;

  auto STAGE = [&](int tile, int unit) {
    int tb = tile & (NT - 1);
    long k0 = (long)tb << 6;
    char* base = smem + (tb & 1) * BUFSZ;
    if (unit < 2) {
#pragma unroll
      for (int j = 0; j < 2; ++j) {
        int row = unit * 128 + j * 64 + srow;
        int ch = schunk ^ (row & 7);
        __builtin_amdgcn_global_load_lds(
            (const AS1 void*)(A + (m0 + row) * K + k0 + ch * 8),
            (AS3 void*)(base + unit * 16384 + j * 8192 + w * 1024 + lane * 16), 16, 0, 0);
      }
    } else {
      int bj = unit - 2;
      int row = bj * 64 + srow;
      int ch = schunk ^ (row & 7);
      __builtin_amdgcn_global_load_lds(
          (const AS1 void*)(B + (n0 + row) * K + k0 + ch * 8),
          (AS3 void*)(base + 32768 + bj * 8192 + w * 1024 + lane * 16), 16, 0, 0);
    }
  };
  auto LDA = [&](int buf, int f, int s) -> short8 {
    int ra = wr * 128 + f * 16 + l15;
    int byte = ra * 128 + (((s << 2) + l4) ^ (ra & 7)) * 16;
    return *(const short8*)(smem + buf * BUFSZ + byte);
  };
  auto LDB = [&](int buf, int g, int s) -> short8 {
    int rb = wc * (G * 16) + g * 16 + l15;
    int byte = 32768 + rb * 128 + (((s << 2) + l4) ^ (rb & 7)) * 16;
    return *(const short8*)(smem + buf * BUFSZ + byte);
  };

#pragma unroll
  for (int u = 0; u < 2 + G; ++u) STAGE(0, u);
  STAGE(1, 0);
  asm volatile("s_waitcnt vmcnt(2)" ::: "memory");
  asm volatile("s_barrier" ::: "memory");

  short8 af[4][2], bf2[G][2];
  for (int tt = 0; tt < NT; ++tt) {
    const int buf = tt & 1;
    // q0
#pragma unroll
    for (int f = 0; f < 4; ++f) { af[f][0] = LDA(buf, f, 0); af[f][1] = LDA(buf, f, 1); }
#pragma unroll
    for (int g = 0; g < GH; ++g) { bf2[g][0] = LDB(buf, g, 0); bf2[g][1] = LDB(buf, g, 1); }
    STAGE(tt + 1, 1);
    asm volatile("s_barrier" ::: "memory");
    __builtin_amdgcn_s_setprio(1);
#pragma unroll
    for (int f = 0; f < 4; ++f)
#pragma unroll
      for (int g = 0; g < GH; ++g) {
        acc[f][g] = __builtin_amdgcn_mfma_f32_16x16x32_bf16(af[f][0], bf2[g][0], acc[f][g], 0, 0, 0);
        acc[f][g] = __builtin_amdgcn_mfma_f32_16x16x32_bf16(af[f][1], bf2[g][1], acc[f][g], 0, 0, 0);
      }
    __builtin_amdgcn_s_setprio(0);
    asm volatile("s_barrier" ::: "memory");
    // q1
#pragma unroll
    for (int g = GH; g < G; ++g) { bf2[g][0] = LDB(buf, g, 0); bf2[g][1] = LDB(buf, g, 1); }
#pragma unroll
    for (int u = 2; u < G + 1; ++u) STAGE(tt + 1, u);
    asm volatile("s_barrier" ::: "memory");
    __builtin_amdgcn_s_setprio(1);
#pragma unroll
    for (int f = 0; f < 4; ++f)
#pragma unroll
      for (int g = GH; g < G; ++g) {
        acc[f][g] = __builtin_amdgcn_mfma_f32_16x16x32_bf16(af[f][0], bf2[g][0], acc[f][g], 0, 0, 0);
        acc[f][g] = __builtin_amdgcn_mfma_f32_16x16x32_bf16(af[f][1], bf2[g][1], acc[f][g], 0, 0, 0);
      }
    __builtin_amdgcn_s_setprio(0);
    asm volatile("s_barrier" ::: "memory");
    // q2
#pragma unroll
    for (int f = 0; f < 4; ++f) { af[f][0] = LDA(buf, 4 + f, 0); af[f][1] = LDA(buf, 4 + f, 1); }
    STAGE(tt + 1, G + 1);
    asm volatile("s_barrier" ::: "memory");
    __builtin_amdgcn_s_setprio(1);
#pragma unroll
    for (int f = 0; f < 4; ++f)
#pragma unroll
      for (int g = 0; g < GH; ++g) {
        acc[4 + f][g] = __builtin_amdgcn_mfma_f32_16x16x32_bf16(af[f][0], bf2[g][0], acc[4 + f][g], 0, 0, 0);
        acc[4 + f][g] = __builtin_amdgcn_mfma_f32_16x16x32_bf16(af[f][1], bf2[g][1], acc[4 + f][g], 0, 0, 0);
      }
    __builtin_amdgcn_s_setprio(0);
    asm volatile("s_barrier" ::: "memory");
    // q3
    STAGE(tt + 2, 0);
    asm volatile("s_barrier" ::: "memory");
    __builtin_amdgcn_s_setprio(1);
#pragma unroll
    for (int f = 0; f < 4; ++f)
#pragma unroll
      for (int g = GH; g < G; ++g) {
        acc[4 + f][g] = __builtin_amdgcn_mfma_f32_16x16x32_bf16(af[f][0], bf2[g][0], acc[4 + f][g], 0, 0, 0);
        acc[4 + f][g] = __builtin_amdgcn_mfma_f32_16x16x32_bf16(af[f][1], bf2[g][1], acc[4 + f][g], 0, 0, 0);
      }
    __builtin_amdgcn_s_setprio(0);
    asm volatile("s_waitcnt vmcnt(2)" ::: "memory");
    asm volatile("s_barrier" ::: "memory");
  }
#pragma unroll
  for (int f = 0; f < 8; ++f)
#pragma unroll
    for (int g = 0; g < G; ++g)
#pragma unroll
      for (int r = 0; r < 4; ++r) {
        long m = m0 + wr * 128 + f * 16 + l4 * 4 + r;
        long n = n0 + wc * (G * 16) + g * 16 + l15;
        C[m * N + n] = acc[f][g][r];
      }
}

// ---------------- RMS norm + partial RoPE (Q and K only) --------------
__global__ __launch_bounds__(256) void normrope_kernel(const float* __restrict__ QKV,
    const int* __restrict__ pos_ids, const float* __restrict__ qw,
    const float* __restrict__ kw,
    short* __restrict__ Qn, short* __restrict__ Kn) {
  const int lane = threadIdx.x & 63;
  const long row = (long)blockIdx.x * 4 + (threadIdx.x >> 6);
  const long NQ = (long)S_ * NH;
  const float* src;
  short* dst;
  const float* wv;
  int s;
  float scl = 1.f;
  if (row < NQ) {
    s = (int)(row >> 5); int h = (int)(row & 31);
    src = QKV + (long)s * 6144 + h * 128;
    dst = Qn + ((long)h * S_ + s) * 128;
    wv = qw; scl = SCL2E_;
  } else {
    long r2 = row - NQ; s = (int)(r2 >> 3); int kh = (int)(r2 & 7);
    src = QKV + (long)s * 6144 + 4096 + kh * 128;
    dst = Kn + ((long)kh * S_ + s) * 128;
    wv = kw;
  }
  float x0 = src[lane], x1 = src[lane + 64];
  float ss = x0 * x0 + x1 * x1;
#pragma unroll
  for (int m = 1; m < 64; m <<= 1) ss += __shfl_xor(ss, m);
  float inv = rsqrtf(ss * (1.f / 128.f) + EPS_);
  x0 = x0 * inv * (wv[lane] + 1.f);
  x1 = x1 * inv * (wv[lane + 64] + 1.f);
  int pos = pos_ids[s];
  int i = lane & 31;
  float invf = expf(-logf(10000.f) * ((float)(2 * i) / 64.f));
  float f = (float)pos * invf;
  float c = cosf(f), sn = sinf(f);
  float p = __shfl_xor(x0, 32);
  x0 = (lane < 32) ? (x0 * c - p * sn) : (x0 * c + p * sn);
  dst[lane] = f2bf(x0 * scl);
  dst[lane + 64] = f2bf(x1 * scl);
}

// ---------------- V transpose: QKVf V-cols -> Vt[kh][128][S] bf16 ------
__global__ __launch_bounds__(256) void vtrans_kernel(const float* __restrict__ QKV,
                                                     short* __restrict__ Vt) {
  __shared__ __align__(16) float lt[64][68];
  const int t = threadIdx.x;
  const int s0 = blockIdx.x * 64, d0 = blockIdx.y * 64, kh = blockIdx.z;
  const float* src = QKV + (long)s0 * 6144 + 5120 + kh * 128 + d0;
#pragma unroll
  for (int i = 0; i < 4; ++i) {
    int idx = t + i * 256;
    int r = idx >> 4, c4 = (idx & 15) * 4;
    float4 v = *(const float4*)(src + (long)r * 6144 + c4);
    *(float4*)&lt[r][c4] = v;
  }
  __syncthreads();
  int d = t >> 2, seg = (t & 3) * 16;
  short* dst = Vt + ((long)kh * 128 + d0 + d) * S_ + s0 + seg;
  short8 a, b2;
#pragma unroll
  for (int j = 0; j < 8; ++j) a[j] = f2bf(lt[seg + j][d]);
#pragma unroll
  for (int j = 0; j < 8; ++j) b2[j] = f2bf(lt[seg + 8 + j][d]);
  *(short8*)dst = a;
  *(short8*)(dst + 8) = b2;
}

// ---------------- causal flash attention, GQA 4:1 ----------------------
// 512 blocks: kh fastest (-> each XCD owns one kv-head's K/V in L2),
// qt descending (LPT). 4 waves x 32 q-rows (QBLK=128), KVBLK=64.
// LDS 48KB single-buffered: K[16K] V[16K] P[4][4K] -> 3 blocks/CU.
// Split-wait: vmcnt(4)+bar (K landed) -> QK+softmax while V in flight ->
// vmcnt(0)+bar -> PV -> bar.
__global__ __launch_bounds__(256, 2) void attn_kernel(const short* __restrict__ Qn,
    const short* __restrict__ Kn, const short* __restrict__ Vt,
    short* __restrict__ O) {
  extern __shared__ __align__(16) char smem[];
  const int t = threadIdx.x, w = t >> 6, lane = t & 63;
  const int b = blockIdx.x;
  const int kh = b & 7, h = kh * 4 + ((b >> 3) & 3), qt = 15 - (b >> 5);
  const int q0 = qt * 128;
  const int l15 = lane & 15, l4 = lane >> 4, lk = l4 * 8;
  const int mrow = l4 * 4;
  char* kd = smem;
  char* vd = smem + 16384;
  char* pw = smem + 32768 + w * 4096;

  // Q fragments: 2 m-frags x 4 k-frags (rows q0 + w*32 + mf*16 + l15)
  short8 qf[2][4];
  {
    const short* Qh = Qn + ((long)h * S_ + q0 + w * 32) * 128;
#pragma unroll
    for (int mf = 0; mf < 2; ++mf)
#pragma unroll
      for (int ks = 0; ks < 4; ++ks)
        qf[mf][ks] = *(const short8*)(Qh + (mf * 16 + l15) * 128 + ks * 32 + lk);
  }
  f32x4 o[2][8];
#pragma unroll
  for (int mf = 0; mf < 2; ++mf)
#pragma unroll
    for (int nf = 0; nf < 8; ++nf) o[mf][nf] = (f32x4){0.f, 0.f, 0.f, 0.f};
  float mrun[2][4], lrun[2][4];
#pragma unroll
  for (int mf = 0; mf < 2; ++mf)
#pragma unroll
    for (int r = 0; r < 4; ++r) { mrun[mf][r] = -1e30f; lrun[mf][r] = 0.f; }

  const short* Khp = Kn + (long)kh * S_ * 128;
  const short* Vtp = Vt + (long)kh * 128 * S_;
  const int NTIL = 2 * qt + 2;

  for (int it = 0; it < NTIL; ++it) {
    const int kv0 = it * 64;
    // ---- stage K (4 glds), then V (4 glds); linear LDS dest,
    //      pre-swizzled global source (chunk ^= row&7) ----
#pragma unroll
    for (int j = 0; j < 4; ++j) {
      int row = (w * 4 + j) * 4 + l4;              // K row 0..63
      int ch = l15 ^ (row & 7);
      __builtin_amdgcn_global_load_lds(
          (const AS1 void*)(Khp + (long)(kv0 + row) * 128 + ch * 8),
          (AS3 void*)(kd + (w * 4 + j) * 1024 + lane * 16), 16, 0, 0);
    }
#pragma unroll
    for (int j = 0; j < 4; ++j) {
      int d = (w * 4 + j) * 8 + (lane >> 3);       // V^T d-row 0..127
      int ch = (lane & 7) ^ (d & 7);
      __builtin_amdgcn_global_load_lds(
          (const AS1 void*)(Vtp + (long)d * S_ + kv0 + ch * 8),
          (AS3 void*)(vd + (w * 4 + j) * 1024 + lane * 16), 16, 0, 0);
    }
    asm volatile("s_waitcnt vmcnt(4)" ::: "memory");   // this wave's K landed
    asm volatile("s_barrier" ::: "memory");            // => all waves' K landed

    const bool active = (kv0 < q0 + w * 32 + 32);
    if (active) {
      // ---- QK^T: 32x64 scores (2 m-frags) ----
      f32x4 sc[2][4];
#pragma unroll
      for (int mf = 0; mf < 2; ++mf)
#pragma unroll
        for (int ni = 0; ni < 4; ++ni) sc[mf][ni] = (f32x4){0.f, 0.f, 0.f, 0.f};
#pragma unroll
      for (int ks = 0; ks < 4; ++ks)
#pragma unroll
        for (int ni = 0; ni < 4; ++ni) {
          int row = ni * 16 + l15;
          int bb = row * 256 + ((((ks << 2) + l4) ^ (row & 7)) << 4);
          short8 kf = *(const short8*)(kd + bb);
          sc[0][ni] = __builtin_amdgcn_mfma_f32_16x16x32_bf16(qf[0][ks], kf, sc[0][ni], 0, 0, 0);
          sc[1][ni] = __builtin_amdgcn_mfma_f32_16x16x32_bf16(qf[1][ks], kf, sc[1][ni], 0, 0, 0);
        }
      // ---- causal mask ----
#pragma unroll
      for (int mf = 0; mf < 2; ++mf)
        if (kv0 + 64 > q0 + w * 32 + mf * 16) {
#pragma unroll
          for (int ni = 0; ni < 4; ++ni)
#pragma unroll
            for (int r = 0; r < 4; ++r) {
              int qm = q0 + w * 32 + mf * 16 + mrow + r;
              int kcol = kv0 + ni * 16 + l15;
              if (kcol > qm) sc[mf][ni][r] = -1e30f;
            }
        }
      // ---- online softmax (log2 domain) + P write (wave-local LDS) ----
#pragma unroll
      for (int mf = 0; mf < 2; ++mf)
#pragma unroll
        for (int r = 0; r < 4; ++r) {
          float mx = fmaxf(fmaxf(sc[mf][0][r], sc[mf][1][r]), fmaxf(sc[mf][2][r], sc[mf][3][r]));
          mx = fmaxf(mx, __shfl_xor(mx, 1));
          mx = fmaxf(mx, __shfl_xor(mx, 2));
          mx = fmaxf(mx, __shfl_xor(mx, 4));
          mx = fmaxf(mx, __shfl_xor(mx, 8));
          float mnew = fmaxf(mrun[mf][r], mx);
          float scale = exp2f(mrun[mf][r] - mnew);
          mrun[mf][r] = mnew;
          float ssum = 0.f;
          short pbv[4];
#pragma unroll
          for (int ni = 0; ni < 4; ++ni) {
            float p = exp2f(sc[mf][ni][r] - mnew);
            ssum += p;
            pbv[ni] = f2bf(p);
          }
          ssum += __shfl_xor(ssum, 1);
          ssum += __shfl_xor(ssum, 2);
          ssum += __shfl_xor(ssum, 4);
          ssum += __shfl_xor(ssum, 8);
          lrun[mf][r] = lrun[mf][r] * scale + ssum;
#pragma unroll
          for (int nf = 0; nf < 8; ++nf) o[mf][nf][r] *= scale;
          int m = mf * 16 + mrow + r;
#pragma unroll
          for (int ni = 0; ni < 4; ++ni) {
            int bb = (m * 128 + (ni * 16 + l15) * 2) ^ ((m & 7) << 4);
            *(short*)(pw + bb) = pbv[ni];
          }
        }
    }
    asm volatile("s_waitcnt vmcnt(0)" ::: "memory");   // V landed (hidden under QK/softmax)
    asm volatile("s_barrier" ::: "memory");
    if (active) {
      // ---- PV: O(32x128) += P(32x64) * V^T ----
#pragma unroll
      for (int ks2 = 0; ks2 < 2; ++ks2) {
        int rq0 = l15, rq1 = 16 + l15;
        short8 pf0 = *(const short8*)(pw + ((rq0 * 128 + (ks2 * 32 + lk) * 2) ^ ((rq0 & 7) << 4)));
        short8 pf1 = *(const short8*)(pw + ((rq1 * 128 + (ks2 * 32 + lk) * 2) ^ ((rq1 & 7) << 4)));
#pragma unroll
        for (int nf = 0; nf < 8; ++nf) {
          int d = nf * 16 + l15;
          int bv = d * 128 + ((((ks2 << 2) + l4) ^ (d & 7)) << 4);
          short8 vf = *(const short8*)(vd + bv);
          o[0][nf] = __builtin_amdgcn_mfma_f32_16x16x32_bf16(pf0, vf, o[0][nf], 0, 0, 0);
          o[1][nf] = __builtin_amdgcn_mfma_f32_16x16x32_bf16(pf1, vf, o[1][nf], 0, 0, 0);
        }
      }
    }
    asm volatile("s_barrier" ::: "memory");            // protect kd/vd before next stage
  }
  // ---- epilogue ----
#pragma unroll
  for (int mf = 0; mf < 2; ++mf)
#pragma unroll
    for (int r = 0; r < 4; ++r) {
      float invl = 1.f / lrun[mf][r];
      int m = q0 + w * 32 + mf * 16 + mrow + r;
#pragma unroll
      for (int nf = 0; nf < 8; ++nf)
        O[(long)m * 4096 + h * 128 + nf * 16 + l15] = f2bf(o[mf][nf][r] * invl);
    }
}

// ---------------- launch -----------------------------------------------
extern "C" void kernel_launch(void* const* d_in, const int* in_sizes, int n_in,
                              void* d_out, int out_size, void* d_ws, size_t ws_size,
                              hipStream_t stream) {
  const float* hidden = (const float*)d_in[0];
  const float* Wq = (const float*)d_in[1];
  const float* Wk = (const float*)d_in[2];
  const float* Wv = (const float*)d_in[3];
  const float* Wo = (const float*)d_in[4];
  const float* qw = (const float*)d_in[5];
  const float* kw = (const float*)d_in[6];
  const int* pos = (const int*)d_in[7];
  float* out = (float*)d_out;

  char* ws = (char*)d_ws;
  short* hid_bf  = (short*)(ws + 0);              // 16 MB (dead after GEMM1)
  short* Wqkv_bf = (short*)(ws + 16777216L);      // 48 MB
  short* Wo_bf   = (short*)(ws + 67108864L);      // 32 MB
  float* QKVf    = (float*)(ws + 100663296L);     // 48 MB
  short* Qn      = (short*)(ws + 150994944L);     // 16 MB
  short* Kn      = (short*)(ws + 167772160L);     // 4 MB
  short* Vt      = (short*)(ws + 171966464L);     // 4 MB
  short* AO      = hid_bf;                        // alias

  (void)hipFuncSetAttribute((const void*)gemm8_bt<3>,
                            hipFuncAttributeMaxDynamicSharedMemorySize, 114688);
  (void)hipFuncSetAttribute((const void*)gemm8_bt<2>,
                            hipFuncAttributeMaxDynamicSharedMemorySize, 98304);
  (void)hipFuncSetAttribute((const void*)attn_kernel,
                            hipFuncAttributeMaxDynamicSharedMemorySize, 49152);

  cast_all_kernel<<<49152, 256, 0, stream>>>(
      (const float4*)hidden, (const float4*)Wq, (const float4*)Wk,
      (const float4*)Wv, (const float4*)Wo,
      (short4v*)hid_bf, (short4v*)Wqkv_bf, (short4v*)Wo_bf);

  // QKV = hidden @ [Wq;Wk;Wv]^T : M=2048, N=6144, K=4096 -> 256 blocks
  gemm8_bt<3><<<dim3(256), 512, 114688, stream>>>(hid_bf, Wqkv_bf, QKVf, S_, 6144, HID_);

  normrope_kernel<<<(S_ * (NH + NKH)) / 4, 256, 0, stream>>>(QKVf, pos, qw, kw, Qn, Kn);
  vtrans_kernel<<<dim3(S_ / 64, 2, NKH), 256, 0, stream>>>(QKVf, Vt);

  // attention: 512 blocks (kh fastest -> XCD-local K/V; qt desc LPT)
  attn_kernel<<<dim3(512), 256, 49152, stream>>>(Qn, Kn, Vt, AO);

  // out = AO @ Wo^T : M=2048, N=4096, K=4096 -> 256 blocks
  gemm8_bt<2><<<dim3(256), 512, 98304, stream>>>(AO, Wo_bf, out, S_, HID_, HID_);
}